// Round 7
// baseline (922.250 us; speedup 1.0000x reference)
//
#include <hip/hip_runtime.h>
#include <hip/hip_bf16.h>

typedef __attribute__((ext_vector_type(8))) short bf16x8;
typedef __attribute__((ext_vector_type(4))) float f32x4;

#define DEVI __device__ __forceinline__

DEVI unsigned short f2bf_bits(float f) {
    __hip_bfloat16 h = __float2bfloat16(f);
    return *reinterpret_cast<unsigned short*>(&h);
}
DEVI float bfbits2f(unsigned short u) {
    __hip_bfloat16 h = *reinterpret_cast<__hip_bfloat16*>(&u);
    return __bfloat162float(h);
}

// async global->LDS, 16B per lane. LDS dest is wave-uniform base + lane*16 (linear).
DEVI void gload_lds16(const void* g, void* lds) {
    __builtin_amdgcn_global_load_lds(
        (const __attribute__((address_space(1))) unsigned int*)g,
        (__attribute__((address_space(3))) unsigned int*)lds, 16, 0, 0);
}

template <int N> DEVI void wait_vm() {
    if constexpr (N == 0) asm volatile("s_waitcnt vmcnt(0)" ::: "memory");
    else if constexpr (N == 3) asm volatile("s_waitcnt vmcnt(3)" ::: "memory");
    else if constexpr (N == 6) asm volatile("s_waitcnt vmcnt(6)" ::: "memory");
    else if constexpr (N == 12) asm volatile("s_waitcnt vmcnt(12)" ::: "memory");
    __builtin_amdgcn_sched_barrier(0);
}

// bijective XCD chunking (m204), then COL-MAJOR within XCD: consecutive blocks on one XCD
// sweep rows of ONE B column-panel -> per-XCD L2 keeps only 1-2 B panels resident.
DEVI int2 remap_cm(int bid, int total, int nrow) {
    int q = total >> 3, r = total & 7, x = bid & 7, l = bid >> 3;
    int seq = (x < r ? x * (q + 1) : r * (q + 1) + (x - r) * q) + l;
    return {seq % nrow, seq / nrow};   // (by=row, bx=col)
}

// ---------------- patchify: x[B,C,384,384] -> patches bf16 [4608][1536] (c-major patch dim) ----
__global__ __launch_bounds__(256) void patchify_kernel(const float* __restrict__ x,
                                                       unsigned short* __restrict__ patches)
{
    size_t t8 = (size_t)blockIdx.x * 256 + threadIdx.x;   // 884,736 threads, 8 floats each
    int jq = (int)(t8 % 48);
    size_t t = t8 / 48;
    int r = (int)(t % 384); t /= 384;
    int c = (int)(t % 6);
    int b = (int)(t / 6);
    int j = jq * 8;
    int gh = r >> 4, p1 = r & 15, gw = j >> 4, p2 = j & 15;
    int prow = b * 576 + gh * 24 + gw;
    int pcol = c * 256 + p1 * 16 + p2;
    const float* src = x + ((((size_t)b * 6 + c) * 384 + r) * 384 + j);
    float4 v0 = ((const float4*)src)[0];
    float4 v1 = ((const float4*)src)[1];
    ushort u[8] = { f2bf_bits(v0.x), f2bf_bits(v0.y), f2bf_bits(v0.z), f2bf_bits(v0.w),
                    f2bf_bits(v1.x), f2bf_bits(v1.y), f2bf_bits(v1.z), f2bf_bits(v1.w) };
    *(int4*)&patches[(size_t)prow * 1536 + pcol] = *(int4*)u;
}

// ---------------- patch-weight convert: W f32 [1536][768] -> Wt bf16 [768][1536'] (k-permuted) --
__global__ __launch_bounds__(256) void convT_patch_kernel(const float* __restrict__ W,
                                                          __hip_bfloat16* __restrict__ Wt)
{
    __shared__ float tile[32][33];
    int n0 = blockIdx.x * 32, kp0 = blockIdx.y * 32;
    int tx = threadIdx.x & 31, ty = threadIdx.x >> 5;
#pragma unroll
    for (int i = 0; i < 4; i++) {
        int kp = kp0 + ty + 8 * i;
        int k = (kp & 255) * 6 + (kp >> 8);   // inverse of k' = c*256 + pp
        tile[ty + 8 * i][tx] = W[(size_t)k * 768 + n0 + tx];
    }
    __syncthreads();
#pragma unroll
    for (int i = 0; i < 4; i++)
        Wt[(size_t)(n0 + ty + 8 * i) * 1536 + kp0 + tx] = __float2bfloat16(tile[tx][ty + 8 * i]);
}

// ---------------- weight convert + transpose: W f32 [K][N] -> Wt bf16 [N][K] ----------------
DEVI void convT_body(const float* __restrict__ W, __hip_bfloat16* __restrict__ Wt,
                     int K, int N, int k0, int n0, int tid)
{
    __shared__ float tile[32][33];
    int tx = tid & 31, ty = tid >> 5;
#pragma unroll
    for (int i = 0; i < 4; i++)
        tile[ty + 8 * i][tx] = W[(size_t)(k0 + ty + 8 * i) * N + n0 + tx];
    __syncthreads();
#pragma unroll
    for (int i = 0; i < 4; i++)
        Wt[(size_t)(n0 + ty + 8 * i) * K + k0 + tx] = __float2bfloat16(tile[tx][ty + 8 * i]);
}

__global__ __launch_bounds__(256) void convT4_kernel(const float* __restrict__ wqkv,
                                                     const float* __restrict__ wout,
                                                     const float* __restrict__ w1,
                                                     const float* __restrict__ w2,
                                                     __hip_bfloat16* __restrict__ dst)
{
    int bt = blockIdx.x;
    const float* W; __hip_bfloat16* Wt; int K, N, lt;
    if (bt < 1728)      { W = wqkv; K = 768;  N = 2304; lt = bt;        Wt = dst; }
    else if (bt < 2304) { W = wout; K = 768;  N = 768;  lt = bt - 1728; Wt = dst + 1769472; }
    else if (bt < 4608) { W = w1;   K = 768;  N = 3072; lt = bt - 2304; Wt = dst + 2359296; }
    else                { W = w2;   K = 3072; N = 768;  lt = bt - 4608; Wt = dst + 4718592; }
    int tn = N >> 5;
    convT_body(W, Wt, K, N, (lt / tn) * 32, (lt % tn) * 32, threadIdx.x);
}

// ---------------- layernorm over 768 cols (templated in/out) ----------------
DEVI float ld_ln(const float* p) { return *p; }
DEVI float ld_ln(const __hip_bfloat16* p) { return __bfloat162float(*p); }
DEVI void st_ln(float* p, float v) { *p = v; }
DEVI void st_ln(__hip_bfloat16* p, float v) { *p = __float2bfloat16(v); }

template <typename InT, typename OutT>
__global__ __launch_bounds__(256) void ln_kernel(const InT* __restrict__ x,
                                                 const float* __restrict__ g,
                                                 const float* __restrict__ b,
                                                 OutT* __restrict__ out)
{
    int row = blockIdx.x, tid = threadIdx.x;
    const InT* xr = x + (size_t)row * 768;
    float v0 = ld_ln(&xr[tid]), v1 = ld_ln(&xr[tid + 256]), v2 = ld_ln(&xr[tid + 512]);
    float s = v0 + v1 + v2;
    float s2 = v0 * v0 + v1 * v1 + v2 * v2;
#pragma unroll
    for (int m = 32; m >= 1; m >>= 1) { s += __shfl_xor(s, m); s2 += __shfl_xor(s2, m); }
    __shared__ float red[8];
    int w = tid >> 6;
    if ((tid & 63) == 0) { red[w] = s; red[4 + w] = s2; }
    __syncthreads();
    s = red[0] + red[1] + red[2] + red[3];
    s2 = red[4] + red[5] + red[6] + red[7];
    float mean = s * (1.0f / 768.0f);
    float var = s2 * (1.0f / 768.0f) - mean * mean;
    float rstd = rsqrtf(var + 1e-5f);
    OutT* orow = out + (size_t)row * 768;
    st_ln(&orow[tid], (v0 - mean) * rstd * g[tid] + b[tid]);
    st_ln(&orow[tid + 256], (v1 - mean) * rstd * g[tid + 256] + b[tid + 256]);
    st_ln(&orow[tid + 512], (v2 - mean) * rstd * g[tid + 512] + b[tid + 512]);
}

// ---------------- narrow GEMM: BM=64 x BN=128, 3-deep counted-vmcnt, bf16 out ----------------
// col-major XCD remap; coalesced epilogue via per-wave LDS transpose; optional bf16 resid
// (added post-transpose from 16B loads; in-place tok += is safe: each elem read by its writer).
template <bool BIAS, bool RESID>
__global__ __launch_bounds__(256, 3) void gemm_bt_kernel(
    const __hip_bfloat16* __restrict__ A,
    const __hip_bfloat16* __restrict__ Bt,
    const float* __restrict__ bias,
    const __hip_bfloat16* __restrict__ resid,
    __hip_bfloat16* __restrict__ Cb,
    int M, int N, int K, int nrow)
{
    constexpr int BM = 64, SL = 3;
    __shared__ __align__(16) __hip_bfloat16 As[3][BM * 32];
    __shared__ __align__(16) __hip_bfloat16 Bs[3][128 * 32];
    const int tid = threadIdx.x;
    const int wid = tid >> 6, lane = tid & 63;
    const int g = lane >> 4, l16 = lane & 15;
    const int wm = (wid >> 1) * 32, wn = (wid & 1) * 64;

    int2 bc = remap_cm(blockIdx.x, gridDim.x, nrow);
    const int bm = bc.x * BM, bn = bc.y * 128;

    const int sr = tid >> 2;
    const int csrc = (lane & 3) ^ ((lane >> 3) & 3);
    const int sdst = sr * 32 + (lane & 3) * 8;
    size_t aOff = (size_t)(bm + sr) * K + csrc * 8;
    size_t bOff[2];
#pragma unroll
    for (int i = 0; i < 2; i++) bOff[i] = (size_t)(bn + i * 64 + sr) * K + csrc * 8;

    auto stage = [&](__hip_bfloat16* asb, __hip_bfloat16* bsb, int tq) {
        const __hip_bfloat16* ap = A + tq * 32;
        const __hip_bfloat16* bp = Bt + tq * 32;
        gload_lds16(ap + aOff, asb + sdst);
#pragma unroll
        for (int i = 0; i < 2; i++) gload_lds16(bp + bOff[i], bsb + i * 2048 + sdst);
    };

    const int pSw = (l16 >> 1) & 3;
    f32x4 acc[2][4] = {};
    const int nt = K >> 5;

    stage(As[0], Bs[0], 0);
    stage(As[1], Bs[1], 1);
    stage(As[2], Bs[2], 2);
    wait_vm<2 * SL>();
    __builtin_amdgcn_s_barrier();
    __builtin_amdgcn_sched_barrier(0);

    for (int t = 0; t < nt; t += 3) {
#pragma unroll
        for (int u = 0; u < 3; u++) {
            const int tc = t + u;
            bf16x8 af[2], bfr[4];
#pragma unroll
            for (int mi = 0; mi < 2; mi++)
                af[mi] = *(const bf16x8*)&As[u][(wm + mi * 16 + l16) * 32 + ((g ^ pSw) << 3)];
#pragma unroll
            for (int ni = 0; ni < 4; ni++)
                bfr[ni] = *(const bf16x8*)&Bs[u][(wn + ni * 16 + l16) * 32 + ((g ^ pSw) << 3)];
#pragma unroll
            for (int mi = 0; mi < 2; mi++)
#pragma unroll
                for (int ni = 0; ni < 4; ni++)
                    acc[mi][ni] = __builtin_amdgcn_mfma_f32_16x16x32_bf16(af[mi], bfr[ni], acc[mi][ni], 0, 0, 0);

            asm volatile("s_waitcnt lgkmcnt(0)" ::: "memory");
            __builtin_amdgcn_sched_barrier(0);
            __builtin_amdgcn_s_barrier();
            __builtin_amdgcn_sched_barrier(0);

            if (tc + 3 < nt) stage(As[u], Bs[u], tc + 3);
            if (tc + 1 < nt) {
                if (tc + 4 <= nt)      wait_vm<2 * SL>();
                else if (tc + 3 == nt) wait_vm<SL>();
                else                   wait_vm<0>();
                __builtin_amdgcn_s_barrier();
                __builtin_amdgcn_sched_barrier(0);
            }
        }
    }

    // epilogue: per-wave LDS transpose (scratch = As, 4608 elems needed <= 6144 avail)
    __hip_bfloat16* scr = &As[0][0] + wid * (16 * 72);
#pragma unroll
    for (int mi = 0; mi < 2; mi++) {
#pragma unroll
        for (int ni = 0; ni < 4; ni++) {
            float bval = 0.0f;
            if (BIAS) bval = bias[bn + wn + ni * 16 + l16];
#pragma unroll
            for (int r = 0; r < 4; r++)
                scr[(4 * g + r) * 72 + ni * 16 + l16] = __float2bfloat16(acc[mi][ni][r] + bval);
        }
        asm volatile("s_waitcnt lgkmcnt(0)" ::: "memory");
        __builtin_amdgcn_sched_barrier(0);
#pragma unroll
        for (int q2 = 0; q2 < 2; q2++) {
            int row16 = q2 * 8 + (lane >> 3), ch = lane & 7;
            bf16x8 vv = *(const bf16x8*)&scr[row16 * 72 + ch * 8];
            int grow = bm + wm + mi * 16 + row16;
            size_t off = (size_t)grow * N + bn + wn + ch * 8;
            if (RESID) {
                bf16x8 rv = *(const bf16x8*)&resid[off];
#pragma unroll
                for (int e = 0; e < 8; e++)
                    vv[e] = (short)f2bf_bits(bfbits2f((unsigned short)vv[e]) + bfbits2f((unsigned short)rv[e]));
            }
            *(int4*)&Cb[off] = *(int4*)&vv;
        }
        asm volatile("s_waitcnt lgkmcnt(0)" ::: "memory");
        __builtin_amdgcn_sched_barrier(0);
    }
}

// ---------------- wide GEMM: BM=128 x BN=256, 3-deep counted-vmcnt, bf16 out ------------------
template <bool BIAS, bool GELU>
__global__ __launch_bounds__(256, 2) void gemm_wide_kernel(
    const __hip_bfloat16* __restrict__ A,
    const __hip_bfloat16* __restrict__ Bt,
    const float* __restrict__ bias,
    __hip_bfloat16* __restrict__ Cb,
    int M, int N, int K, int nrow)
{
    constexpr int SL = 6;
    __shared__ __align__(16) __hip_bfloat16 As[3][128 * 32];
    __shared__ __align__(16) __hip_bfloat16 Bs[3][256 * 32];
    const int tid = threadIdx.x;
    const int wid = tid >> 6, lane = tid & 63;
    const int g = lane >> 4, l16 = lane & 15;
    const int wm = (wid >> 1) * 64, wn = (wid & 1) * 128;

    int2 bc = remap_cm(blockIdx.x, gridDim.x, nrow);
    const int bm = bc.x * 128, bn = bc.y * 256;

    const int sr = tid >> 2;
    const int csrc = (lane & 3) ^ ((lane >> 3) & 3);
    const int sdst = sr * 32 + (lane & 3) * 8;
    size_t aOff[2], bOff[4];
#pragma unroll
    for (int i = 0; i < 2; i++) aOff[i] = (size_t)(bm + i * 64 + sr) * K + csrc * 8;
#pragma unroll
    for (int i = 0; i < 4; i++) bOff[i] = (size_t)(bn + i * 64 + sr) * K + csrc * 8;

    auto stage = [&](__hip_bfloat16* asb, __hip_bfloat16* bsb, int tq) {
        const __hip_bfloat16* ap = A + tq * 32;
        const __hip_bfloat16* bp = Bt + tq * 32;
#pragma unroll
        for (int i = 0; i < 2; i++) gload_lds16(ap + aOff[i], asb + i * 2048 + sdst);
#pragma unroll
        for (int i = 0; i < 4; i++) gload_lds16(bp + bOff[i], bsb + i * 2048 + sdst);
    };

    const int pSw = (l16 >> 1) & 3;
    f32x4 acc[4][8] = {};
    const int nt = K >> 5;

    stage(As[0], Bs[0], 0);
    stage(As[1], Bs[1], 1);
    stage(As[2], Bs[2], 2);
    wait_vm<2 * SL>();
    __builtin_amdgcn_s_barrier();
    __builtin_amdgcn_sched_barrier(0);

    for (int t = 0; t < nt; t += 3) {
#pragma unroll
        for (int u = 0; u < 3; u++) {
            const int tc = t + u;
            bf16x8 af[4], bfr[8];
#pragma unroll
            for (int mi = 0; mi < 4; mi++)
                af[mi] = *(const bf16x8*)&As[u][(wm + mi * 16 + l16) * 32 + ((g ^ pSw) << 3)];
#pragma unroll
            for (int ni = 0; ni < 8; ni++)
                bfr[ni] = *(const bf16x8*)&Bs[u][(wn + ni * 16 + l16) * 32 + ((g ^ pSw) << 3)];
#pragma unroll
            for (int mi = 0; mi < 4; mi++)
#pragma unroll
                for (int ni = 0; ni < 8; ni++)
                    acc[mi][ni] = __builtin_amdgcn_mfma_f32_16x16x32_bf16(af[mi], bfr[ni], acc[mi][ni], 0, 0, 0);

            asm volatile("s_waitcnt lgkmcnt(0)" ::: "memory");
            __builtin_amdgcn_sched_barrier(0);
            __builtin_amdgcn_s_barrier();
            __builtin_amdgcn_sched_barrier(0);

            if (tc + 3 < nt) stage(As[u], Bs[u], tc + 3);
            if (tc + 1 < nt) {
                if (tc + 4 <= nt)      wait_vm<2 * SL>();
                else if (tc + 3 == nt) wait_vm<SL>();
                else                   wait_vm<0>();
                __builtin_amdgcn_s_barrier();
                __builtin_amdgcn_sched_barrier(0);
            }
        }
    }

    // coalesced epilogue via per-wave LDS transpose (rows padded to 136 elems)
    __hip_bfloat16* scr = &As[0][0] + wid * (16 * 136);
#pragma unroll
    for (int mi = 0; mi < 4; mi++) {
#pragma unroll
        for (int ni = 0; ni < 8; ni++) {
            float bval = 0.0f;
            if (BIAS) bval = bias[bn + wn + ni * 16 + l16];
#pragma unroll
            for (int r = 0; r < 4; r++) {
                float v = acc[mi][ni][r] + bval;
                if (GELU) v = 0.5f * v * (1.0f + erff(v * 0.70710678118654752f));
                scr[(4 * g + r) * 136 + ni * 16 + l16] = __float2bfloat16(v);
            }
        }
        asm volatile("s_waitcnt lgkmcnt(0)" ::: "memory");
        __builtin_amdgcn_sched_barrier(0);
#pragma unroll
        for (int q2 = 0; q2 < 4; q2++) {
            int idx = q2 * 64 + lane;
            int row16 = idx >> 4, ch = idx & 15;
            bf16x8 vv = *(const bf16x8*)&scr[row16 * 136 + ch * 8];
            int grow = bm + wm + mi * 16 + row16;
            *(int4*)&Cb[(size_t)grow * N + bn + wn + ch * 8] = *(int4*)&vv;
        }
        asm volatile("s_waitcnt lgkmcnt(0)" ::: "memory");
        __builtin_amdgcn_sched_barrier(0);
    }
}

// ---------------- MFMA flash attention: softmax(q@k^T*scale + bias) @ v ----------------
__global__ __launch_bounds__(256) void attn_kernel(const __hip_bfloat16* __restrict__ qkvb,
                                                   const float* __restrict__ bias,   // [12][576][576] this layer
                                                   unsigned short* __restrict__ o)   // bf16 [4608][768]
{
    const int seq = (blockIdx.x & 7) * 108 + (blockIdx.x >> 3);
    const int bb = seq & 7, qt = (seq >> 3) % 9, h = seq / 72;
    const int q0 = qt * 64;
    const int tid = threadIdx.x;
    const int wq = tid >> 6, lane = tid & 63, g = lane >> 4, l16 = lane & 15;

    __shared__ __align__(16) unsigned short Qs[64 * 72];
    __shared__ __align__(16) unsigned short Ks[64 * 72];
    __shared__ __align__(16) unsigned short Vt[64 * 72];
    __shared__ __align__(16) unsigned short Ps[4][16 * 72];

    {
        int r = tid >> 2, cb = (tid & 3) * 16;
        const int4* s4 = (const int4*)&qkvb[(size_t)(bb * 576 + q0 + r) * 2304 + h * 64 + cb];
        int4* d4 = (int4*)&Qs[r * 72 + cb];
        d4[0] = s4[0]; d4[1] = s4[1];
    }
    __syncthreads();
    bf16x8 qf0 = *(const bf16x8*)&Qs[(wq * 16 + l16) * 72 + g * 8];
    bf16x8 qf1 = *(const bf16x8*)&Qs[(wq * 16 + l16) * 72 + 32 + g * 8];

    float m_r[4] = {-1e30f, -1e30f, -1e30f, -1e30f};
    float l_r[4] = {0.f, 0.f, 0.f, 0.f};
    f32x4 oa[4] = {};
    const float* bias_h = bias + (size_t)h * 576 * 576;
    const float scale = 0.125f;

    for (int kt = 0; kt < 576; kt += 64) {
        {
            int r = tid >> 2, cb = (tid & 3) * 16;
            const int4* s4 = (const int4*)&qkvb[(size_t)(bb * 576 + kt + r) * 2304 + 768 + h * 64 + cb];
            int4* d4 = (int4*)&Ks[r * 72 + cb];
            d4[0] = s4[0]; d4[1] = s4[1];
            int key = tid & 63, d0 = (tid >> 6) * 16;
            const unsigned short* vs = (const unsigned short*)&qkvb[(size_t)(bb * 576 + kt + key) * 2304 + 1536 + h * 64 + d0];
            bf16x8 v0 = *(const bf16x8*)vs;
            bf16x8 v1 = *(const bf16x8*)(vs + 8);
#pragma unroll
            for (int e = 0; e < 8; e++) {
                Vt[(d0 + e) * 72 + key] = (unsigned short)v0[e];
                Vt[(d0 + 8 + e) * 72 + key] = (unsigned short)v1[e];
            }
        }
        __syncthreads();

        float bl[4][4];
#pragma unroll
        for (int kc = 0; kc < 4; kc++)
#pragma unroll
            for (int r = 0; r < 4; r++) {
                int q = q0 + wq * 16 + 4 * g + r;
                bl[kc][r] = bias_h[(size_t)q * 576 + kt + kc * 16 + l16];
            }

        f32x4 sc[4] = {};
        __builtin_amdgcn_s_setprio(1);
#pragma unroll
        for (int kc = 0; kc < 4; kc++) {
            bf16x8 kf0 = *(const bf16x8*)&Ks[(kc * 16 + l16) * 72 + g * 8];
            bf16x8 kf1 = *(const bf16x8*)&Ks[(kc * 16 + l16) * 72 + 32 + g * 8];
            sc[kc] = __builtin_amdgcn_mfma_f32_16x16x32_bf16(qf0, kf0, sc[kc], 0, 0, 0);
            sc[kc] = __builtin_amdgcn_mfma_f32_16x16x32_bf16(qf1, kf1, sc[kc], 0, 0, 0);
        }
        __builtin_amdgcn_s_setprio(0);

        float sv[4][4], mt[4] = {-1e30f, -1e30f, -1e30f, -1e30f};
#pragma unroll
        for (int kc = 0; kc < 4; kc++)
#pragma unroll
            for (int r = 0; r < 4; r++) {
                float s = sc[kc][r] * scale + bl[kc][r];
                sv[kc][r] = s;
                mt[r] = fmaxf(mt[r], s);
            }
#pragma unroll
        for (int r = 0; r < 4; r++)
#pragma unroll
            for (int m = 1; m < 16; m <<= 1) mt[r] = fmaxf(mt[r], __shfl_xor(mt[r], m));

        float sf[4];
#pragma unroll
        for (int r = 0; r < 4; r++) {
            float mn = fmaxf(m_r[r], mt[r]);
            sf[r] = __expf(m_r[r] - mn);
            m_r[r] = mn;
        }
        float rs[4] = {0.f, 0.f, 0.f, 0.f};
#pragma unroll
        for (int kc = 0; kc < 4; kc++)
#pragma unroll
            for (int r = 0; r < 4; r++) {
                float p = __expf(sv[kc][r] - m_r[r]);
                rs[r] += p;
                Ps[wq][(4 * g + r) * 72 + kc * 16 + l16] = f2bf_bits(p);
            }
#pragma unroll
        for (int r = 0; r < 4; r++) {
#pragma unroll
            for (int m = 1; m < 16; m <<= 1) rs[r] += __shfl_xor(rs[r], m);
            l_r[r] = l_r[r] * sf[r] + rs[r];
        }
#pragma unroll
        for (int dt = 0; dt < 4; dt++)
#pragma unroll
            for (int r = 0; r < 4; r++) oa[dt][r] *= sf[r];

        asm volatile("s_waitcnt lgkmcnt(0)" ::: "memory");

        __builtin_amdgcn_s_setprio(1);
#pragma unroll
        for (int s = 0; s < 2; s++) {
            bf16x8 pf = *(const bf16x8*)&Ps[wq][l16 * 72 + s * 32 + g * 8];
#pragma unroll
            for (int dt = 0; dt < 4; dt++) {
                bf16x8 vf = *(const bf16x8*)&Vt[(dt * 16 + l16) * 72 + s * 32 + g * 8];
                oa[dt] = __builtin_amdgcn_mfma_f32_16x16x32_bf16(pf, vf, oa[dt], 0, 0, 0);
            }
        }
        __builtin_amdgcn_s_setprio(0);
        __syncthreads();
    }

#pragma unroll
    for (int dt = 0; dt < 4; dt++)
#pragma unroll
        for (int r = 0; r < 4; r++) {
            int q = q0 + wq * 16 + 4 * g + r;
            float v = oa[dt][r] / l_r[r];
            o[(size_t)(bb * 576 + q) * 768 + h * 64 + dt * 16 + l16] = f2bf_bits(v);
        }
}

// ---------------- mean pool over 576 tokens (bf16 in) ----------------
__global__ __launch_bounds__(256) void pool_kernel(const __hip_bfloat16* __restrict__ tok,
                                                   float* __restrict__ pooled)
{
    int d = blockIdx.x * 256 + threadIdx.x;
    int b = blockIdx.y;
    float s = 0.0f;
    for (int n = 0; n < 576; n++) s += __bfloat162float(tok[(size_t)(b * 576 + n) * 768 + d]);
    pooled[b * 768 + d] = s * (1.0f / 576.0f);
}

// ---------------- classifier head ----------------
__global__ __launch_bounds__(256) void head_kernel(const float* __restrict__ lnp,
                                                   const float* __restrict__ w,
                                                   const float* __restrict__ bh,
                                                   float* __restrict__ out)
{
    int c = blockIdx.x * 256 + threadIdx.x;
    int b = blockIdx.y;
    if (c >= 1000) return;
    float s = bh[c];
    for (int d = 0; d < 768; d++) s += lnp[b * 768 + d] * w[(size_t)d * 1000 + c];
    out[b * 1000 + c] = s;
}

extern "C" void kernel_launch(void* const* d_in, const int* in_sizes, int n_in,
                              void* d_out, int out_size, void* d_ws, size_t ws_size,
                              hipStream_t stream)
{
    const float* x = (const float*)d_in[0];
    const float* patch_w = (const float*)d_in[1];
    const float* patch_b = (const float*)d_in[2];
    const float* ln1_g = (const float*)d_in[3];
    const float* ln1_b = (const float*)d_in[4];
    const float* w_qkv = (const float*)d_in[5];
    const float* bias_att = (const float*)d_in[6];
    const float* w_out = (const float*)d_in[7];
    const float* ln2_g = (const float*)d_in[8];
    const float* ln2_b = (const float*)d_in[9];
    const float* w1 = (const float*)d_in[10];
    const float* b1 = (const float*)d_in[11];
    const float* w2 = (const float*)d_in[12];
    const float* b2 = (const float*)d_in[13];
    const float* lnh_g = (const float*)d_in[14];
    const float* lnh_b = (const float*)d_in[15];
    const float* w_head = (const float*)d_in[16];
    const float* b_head = (const float*)d_in[17];
    float* out = (float*)d_out;

    char* ws = (char*)d_ws;
    __hip_bfloat16* tok = (__hip_bfloat16*)(ws + 0);             // 4608*768 bf16 = 7,077,888 B
    __hip_bfloat16* qkv_bf = (__hip_bfloat16*)(ws + 14155776);   // 4608*2304 bf16
    float* pooled = (float*)(ws + 56623104);
    float* pooledln = (float*)(ws + 56647680);
    __hip_bfloat16* patches = (__hip_bfloat16*)(ws + 56672256);  // 4608*1536 bf16
    __hip_bfloat16* lw = patches;                                // layer weights reuse after patch GEMM
    __hip_bfloat16* h_bf = (__hip_bfloat16*)(ws + 70828032);
    __hip_bfloat16* o_bf = (__hip_bfloat16*)(ws + 77905920);
    __hip_bfloat16* hid_bf = (__hip_bfloat16*)(ws + 84983808);
    __hip_bfloat16* wbuf = (__hip_bfloat16*)(ws + 113295360);    // patch weight 768*1536 bf16

    // patch embedding
    patchify_kernel<<<3456, 256, 0, stream>>>(x, (unsigned short*)patches);
    convT_patch_kernel<<<dim3(24, 48), 256, 0, stream>>>(patch_w, wbuf);
    gemm_bt_kernel<true, false><<<432, 256, 0, stream>>>(
        patches, wbuf, patch_b, nullptr, tok, 4608, 768, 1536, 72);

    for (int l = 0; l < 4; l++) {
        convT4_kernel<<<6912, 256, 0, stream>>>(
            w_qkv + (size_t)l * 768 * 2304, w_out + (size_t)l * 768 * 768,
            w1 + (size_t)l * 768 * 3072, w2 + (size_t)l * 3072 * 768, lw);
        // attn sub-block
        ln_kernel<__hip_bfloat16, __hip_bfloat16><<<4608, 256, 0, stream>>>(
            tok, ln1_g + l * 768, ln1_b + l * 768, h_bf);
        gemm_wide_kernel<false, false><<<324, 256, 0, stream>>>(
            h_bf, lw, nullptr, qkv_bf, 4608, 2304, 768, 36);
        attn_kernel<<<864, 256, 0, stream>>>(
            qkv_bf, bias_att + (size_t)l * 12 * 576 * 576, (unsigned short*)o_bf);
        gemm_bt_kernel<false, true><<<432, 256, 0, stream>>>(
            o_bf, lw + 1769472, nullptr, tok, tok, 4608, 768, 768, 72);
        // mlp sub-block
        ln_kernel<__hip_bfloat16, __hip_bfloat16><<<4608, 256, 0, stream>>>(
            tok, ln2_g + l * 768, ln2_b + l * 768, h_bf);
        gemm_wide_kernel<true, true><<<432, 256, 0, stream>>>(
            h_bf, lw + 2359296, b1 + l * 3072, hid_bf, 4608, 3072, 768, 36);
        gemm_bt_kernel<true, true><<<432, 256, 0, stream>>>(
            hid_bf, lw + 4718592, b2 + l * 768, tok, tok, 4608, 768, 3072, 72);
    }

    pool_kernel<<<dim3(3, 8), 256, 0, stream>>>(tok, pooled);
    ln_kernel<float, float><<<8, 256, 0, stream>>>(pooled, lnh_g, lnh_b, pooledln);
    head_kernel<<<dim3(4, 8), 256, 0, stream>>>(pooledln, w_head, b_head, out);
}

// Round 8
// 845.436 us; speedup vs baseline: 1.0909x; 1.0909x over previous
//
#include <hip/hip_runtime.h>
#include <hip/hip_bf16.h>

typedef __attribute__((ext_vector_type(8))) short bf16x8;
typedef __attribute__((ext_vector_type(4))) float f32x4;

#define DEVI __device__ __forceinline__

DEVI unsigned short f2bf_bits(float f) {
    __hip_bfloat16 h = __float2bfloat16(f);
    return *reinterpret_cast<unsigned short*>(&h);
}
DEVI float bfbits2f(unsigned short u) {
    __hip_bfloat16 h = *reinterpret_cast<__hip_bfloat16*>(&u);
    return __bfloat162float(h);
}

// async global->LDS, 16B per lane. LDS dest is wave-uniform base + lane*16 (linear).
DEVI void gload_lds16(const void* g, void* lds) {
    __builtin_amdgcn_global_load_lds(
        (const __attribute__((address_space(1))) unsigned int*)g,
        (__attribute__((address_space(3))) unsigned int*)lds, 16, 0, 0);
}

template <int N> DEVI void wait_vm() {
    if constexpr (N == 0) asm volatile("s_waitcnt vmcnt(0)" ::: "memory");
    else if constexpr (N == 6) asm volatile("s_waitcnt vmcnt(6)" ::: "memory");
    else if constexpr (N == 12) asm volatile("s_waitcnt vmcnt(12)" ::: "memory");
    __builtin_amdgcn_sched_barrier(0);
}

// bijective XCD chunking (m204) + group-of-4-rows 2D locality within each XCD's chunk.
DEVI int2 remap2d(int bid, int total, int gx) {
    int q = total >> 3, r = total & 7, x = bid & 7, l = bid >> 3;
    int seq = (x < r ? x * (q + 1) : r * (q + 1) + (x - r) * q) + l;
    int g4 = seq / (4 * gx);
    int rem = seq - g4 * 4 * gx;
    return {g4 * 4 + (rem & 3), rem >> 2};   // (by, bx)
}

// ---------------- patchify: x[B,C,384,384] -> patches bf16 [4608][1536] (c-major patch dim) ----
__global__ __launch_bounds__(256) void patchify_kernel(const float* __restrict__ x,
                                                       unsigned short* __restrict__ patches)
{
    size_t t8 = (size_t)blockIdx.x * 256 + threadIdx.x;   // 884,736 threads, 8 floats each
    int jq = (int)(t8 % 48);
    size_t t = t8 / 48;
    int r = (int)(t % 384); t /= 384;
    int c = (int)(t % 6);
    int b = (int)(t / 6);
    int j = jq * 8;
    int gh = r >> 4, p1 = r & 15, gw = j >> 4, p2 = j & 15;
    int prow = b * 576 + gh * 24 + gw;
    int pcol = c * 256 + p1 * 16 + p2;
    const float* src = x + ((((size_t)b * 6 + c) * 384 + r) * 384 + j);
    float4 v0 = ((const float4*)src)[0];
    float4 v1 = ((const float4*)src)[1];
    ushort u[8] = { f2bf_bits(v0.x), f2bf_bits(v0.y), f2bf_bits(v0.z), f2bf_bits(v0.w),
                    f2bf_bits(v1.x), f2bf_bits(v1.y), f2bf_bits(v1.z), f2bf_bits(v1.w) };
    *(int4*)&patches[(size_t)prow * 1536 + pcol] = *(int4*)u;
}

// ---------------- patch-weight convert: W f32 [1536][768] -> Wt bf16 [768][1536'] (k-permuted) --
__global__ __launch_bounds__(256) void convT_patch_kernel(const float* __restrict__ W,
                                                          __hip_bfloat16* __restrict__ Wt)
{
    __shared__ float tile[32][33];
    int n0 = blockIdx.x * 32, kp0 = blockIdx.y * 32;
    int tx = threadIdx.x & 31, ty = threadIdx.x >> 5;
#pragma unroll
    for (int i = 0; i < 4; i++) {
        int kp = kp0 + ty + 8 * i;
        int k = (kp & 255) * 6 + (kp >> 8);   // inverse of k' = c*256 + pp
        tile[ty + 8 * i][tx] = W[(size_t)k * 768 + n0 + tx];
    }
    __syncthreads();
#pragma unroll
    for (int i = 0; i < 4; i++)
        Wt[(size_t)(n0 + ty + 8 * i) * 1536 + kp0 + tx] = __float2bfloat16(tile[tx][ty + 8 * i]);
}

// ---------------- weight convert + transpose: W f32 [K][N] -> Wt bf16 [N][K] ----------------
DEVI void convT_body(const float* __restrict__ W, __hip_bfloat16* __restrict__ Wt,
                     int K, int N, int k0, int n0, int tid)
{
    __shared__ float tile[32][33];
    int tx = tid & 31, ty = tid >> 5;
#pragma unroll
    for (int i = 0; i < 4; i++)
        tile[ty + 8 * i][tx] = W[(size_t)(k0 + ty + 8 * i) * N + n0 + tx];
    __syncthreads();
#pragma unroll
    for (int i = 0; i < 4; i++)
        Wt[(size_t)(n0 + ty + 8 * i) * K + k0 + tx] = __float2bfloat16(tile[tx][ty + 8 * i]);
}

__global__ __launch_bounds__(256) void convT4_kernel(const float* __restrict__ wqkv,
                                                     const float* __restrict__ wout,
                                                     const float* __restrict__ w1,
                                                     const float* __restrict__ w2,
                                                     __hip_bfloat16* __restrict__ dst)
{
    int bt = blockIdx.x;
    const float* W; __hip_bfloat16* Wt; int K, N, lt;
    if (bt < 1728)      { W = wqkv; K = 768;  N = 2304; lt = bt;        Wt = dst; }
    else if (bt < 2304) { W = wout; K = 768;  N = 768;  lt = bt - 1728; Wt = dst + 1769472; }
    else if (bt < 4608) { W = w1;   K = 768;  N = 3072; lt = bt - 2304; Wt = dst + 2359296; }
    else                { W = w2;   K = 3072; N = 768;  lt = bt - 4608; Wt = dst + 4718592; }
    int tn = N >> 5;
    convT_body(W, Wt, K, N, (lt / tn) * 32, (lt % tn) * 32, threadIdx.x);
}

// ---------------- layernorm over 768 cols (templated in/out) ----------------
DEVI float ld_ln(const float* p) { return *p; }
DEVI float ld_ln(const __hip_bfloat16* p) { return __bfloat162float(*p); }
DEVI void st_ln(float* p, float v) { *p = v; }
DEVI void st_ln(__hip_bfloat16* p, float v) { *p = __float2bfloat16(v); }

template <typename InT, typename OutT>
__global__ __launch_bounds__(256) void ln_kernel(const InT* __restrict__ x,
                                                 const float* __restrict__ g,
                                                 const float* __restrict__ b,
                                                 OutT* __restrict__ out)
{
    int row = blockIdx.x, tid = threadIdx.x;
    const InT* xr = x + (size_t)row * 768;
    float v0 = ld_ln(&xr[tid]), v1 = ld_ln(&xr[tid + 256]), v2 = ld_ln(&xr[tid + 512]);
    float s = v0 + v1 + v2;
    float s2 = v0 * v0 + v1 * v1 + v2 * v2;
#pragma unroll
    for (int m = 32; m >= 1; m >>= 1) { s += __shfl_xor(s, m); s2 += __shfl_xor(s2, m); }
    __shared__ float red[8];
    int w = tid >> 6;
    if ((tid & 63) == 0) { red[w] = s; red[4 + w] = s2; }
    __syncthreads();
    s = red[0] + red[1] + red[2] + red[3];
    s2 = red[4] + red[5] + red[6] + red[7];
    float mean = s * (1.0f / 768.0f);
    float var = s2 * (1.0f / 768.0f) - mean * mean;
    float rstd = rsqrtf(var + 1e-5f);
    OutT* orow = out + (size_t)row * 768;
    st_ln(&orow[tid], (v0 - mean) * rstd * g[tid] + b[tid]);
    st_ln(&orow[tid + 256], (v1 - mean) * rstd * g[tid + 256] + b[tid + 256]);
    st_ln(&orow[tid + 512], (v2 - mean) * rstd * g[tid + 512] + b[tid + 512]);
}

// ---------------- narrow GEMM: BM=64 x BN=128, BK=64, 3-deep counted-vmcnt, bf16 out ----------
// LDS rows are 128B = 8 chunks of 16B; chunk swizzle: phys p of row r holds logical chunk
// p ^ (r&7) (applied on per-lane GLOBAL source; gload dest stays linear; ds_read XORs the
// chunk position). 16-way conflict -> uniform 8-lanes/chunk-group (minimum, free).
template <bool BIAS, bool RESID>
__global__ __launch_bounds__(256, 2) void gemm_bt_kernel(
    const __hip_bfloat16* __restrict__ A,
    const __hip_bfloat16* __restrict__ Bt,
    const float* __restrict__ bias,
    const __hip_bfloat16* __restrict__ resid,
    __hip_bfloat16* __restrict__ Cb,
    int M, int N, int K, int gx)
{
    constexpr int BM = 64, SL = 6;   // per-thread gload calls per tile: 2 A + 4 B
    __shared__ __align__(16) __hip_bfloat16 As[3][BM * 64];
    __shared__ __align__(16) __hip_bfloat16 Bs[3][128 * 64];
    const int tid = threadIdx.x;
    const int wid = tid >> 6, lane = tid & 63;
    const int g = lane >> 4, l16 = lane & 15;
    const int wm = (wid >> 1) * 32, wn = (wid & 1) * 64;

    int2 bc = remap2d(blockIdx.x, gridDim.x, gx);
    const int bm = bc.x * BM, bn = bc.y * 128;

    // staging: 256 threads x 16B = 32 rows x 128B per round; source chunk row-XOR'd
    const int sr32 = tid >> 3, ci = tid & 7;
    const int cg = ci ^ (sr32 & 7);
    const int sdst = tid * 8;             // elems within a 32-row (2048-elem) group
    size_t aOff[2], bOff[4];
#pragma unroll
    for (int i = 0; i < 2; i++) aOff[i] = (size_t)(bm + i * 32 + sr32) * K + cg * 8;
#pragma unroll
    for (int i = 0; i < 4; i++) bOff[i] = (size_t)(bn + i * 32 + sr32) * K + cg * 8;

    auto stage = [&](__hip_bfloat16* asb, __hip_bfloat16* bsb, int tq) {
        const __hip_bfloat16* ap = A + tq * 64;
        const __hip_bfloat16* bp = Bt + tq * 64;
#pragma unroll
        for (int i = 0; i < 2; i++) gload_lds16(ap + aOff[i], asb + i * 2048 + sdst);
#pragma unroll
        for (int i = 0; i < 4; i++) gload_lds16(bp + bOff[i], bsb + i * 2048 + sdst);
    };

    f32x4 acc[2][4] = {};
    const int nt = K >> 6;   // 24 / 12 / 48 for K = 1536 / 768 / 3072 — all divisible by 3

    stage(As[0], Bs[0], 0);
    stage(As[1], Bs[1], 1);
    stage(As[2], Bs[2], 2);
    wait_vm<2 * SL>();
    __builtin_amdgcn_s_barrier();
    __builtin_amdgcn_sched_barrier(0);

    for (int t = 0; t < nt; t += 3) {
#pragma unroll
        for (int u = 0; u < 3; u++) {
            const int tc = t + u;
            bf16x8 af[2][2], bfr[2][4];
#pragma unroll
            for (int s = 0; s < 2; s++) {
                const int cp = ((s * 4 + g) ^ (l16 & 7)) << 3;   // swizzled chunk position
#pragma unroll
                for (int mi = 0; mi < 2; mi++)
                    af[s][mi] = *(const bf16x8*)&As[u][(wm + mi * 16 + l16) * 64 + cp];
#pragma unroll
                for (int ni = 0; ni < 4; ni++)
                    bfr[s][ni] = *(const bf16x8*)&Bs[u][(wn + ni * 16 + l16) * 64 + cp];
            }
#pragma unroll
            for (int s = 0; s < 2; s++)
#pragma unroll
                for (int mi = 0; mi < 2; mi++)
#pragma unroll
                    for (int ni = 0; ni < 4; ni++)
                        acc[mi][ni] = __builtin_amdgcn_mfma_f32_16x16x32_bf16(af[s][mi], bfr[s][ni], acc[mi][ni], 0, 0, 0);

            asm volatile("s_waitcnt lgkmcnt(0)" ::: "memory");
            __builtin_amdgcn_sched_barrier(0);
            __builtin_amdgcn_s_barrier();
            __builtin_amdgcn_sched_barrier(0);

            if (tc + 3 < nt) stage(As[u], Bs[u], tc + 3);
            if (tc + 1 < nt) {
                if (tc + 4 <= nt)      wait_vm<2 * SL>();
                else if (tc + 3 == nt) wait_vm<SL>();
                else                   wait_vm<0>();
                __builtin_amdgcn_s_barrier();
                __builtin_amdgcn_sched_barrier(0);
            }
        }
    }

    // epilogue: per-wave LDS transpose (scratch in As: 4 waves x 1152 <= 12288 elems)
    __hip_bfloat16* scr = &As[0][0] + wid * (16 * 72);
#pragma unroll
    for (int mi = 0; mi < 2; mi++) {
#pragma unroll
        for (int ni = 0; ni < 4; ni++) {
            float bval = 0.0f;
            if (BIAS) bval = bias[bn + wn + ni * 16 + l16];
#pragma unroll
            for (int r = 0; r < 4; r++)
                scr[(4 * g + r) * 72 + ni * 16 + l16] = __float2bfloat16(acc[mi][ni][r] + bval);
        }
        asm volatile("s_waitcnt lgkmcnt(0)" ::: "memory");
        __builtin_amdgcn_sched_barrier(0);
#pragma unroll
        for (int q2 = 0; q2 < 2; q2++) {
            int row16 = q2 * 8 + (lane >> 3), ch = lane & 7;
            bf16x8 vv = *(const bf16x8*)&scr[row16 * 72 + ch * 8];
            int grow = bm + wm + mi * 16 + row16;
            size_t off = (size_t)grow * N + bn + wn + ch * 8;
            if (RESID) {
                bf16x8 rv = *(const bf16x8*)&resid[off];
#pragma unroll
                for (int e = 0; e < 8; e++)
                    vv[e] = (short)f2bf_bits(bfbits2f((unsigned short)vv[e]) + bfbits2f((unsigned short)rv[e]));
            }
            *(int4*)&Cb[off] = *(int4*)&vv;
        }
        asm volatile("s_waitcnt lgkmcnt(0)" ::: "memory");
        __builtin_amdgcn_sched_barrier(0);
    }
}

// ---------------- wide GEMM: BM=128 x BN=256, BK=32, 3-deep counted-vmcnt, bf16 out -----------
template <bool BIAS, bool GELU>
__global__ __launch_bounds__(256, 2) void gemm_wide_kernel(
    const __hip_bfloat16* __restrict__ A,
    const __hip_bfloat16* __restrict__ Bt,
    const float* __restrict__ bias,
    __hip_bfloat16* __restrict__ Cb,
    int M, int N, int K, int gx)
{
    constexpr int SL = 6;
    __shared__ __align__(16) __hip_bfloat16 As[3][128 * 32];
    __shared__ __align__(16) __hip_bfloat16 Bs[3][256 * 32];
    const int tid = threadIdx.x;
    const int wid = tid >> 6, lane = tid & 63;
    const int g = lane >> 4, l16 = lane & 15;
    const int wm = (wid >> 1) * 64, wn = (wid & 1) * 128;

    int2 bc = remap2d(blockIdx.x, gridDim.x, gx);
    const int bm = bc.x * 128, bn = bc.y * 256;

    const int sr = tid >> 2;
    const int csrc = (lane & 3) ^ ((lane >> 3) & 3);
    const int sdst = sr * 32 + (lane & 3) * 8;
    size_t aOff[2], bOff[4];
#pragma unroll
    for (int i = 0; i < 2; i++) aOff[i] = (size_t)(bm + i * 64 + sr) * K + csrc * 8;
#pragma unroll
    for (int i = 0; i < 4; i++) bOff[i] = (size_t)(bn + i * 64 + sr) * K + csrc * 8;

    auto stage = [&](__hip_bfloat16* asb, __hip_bfloat16* bsb, int tq) {
        const __hip_bfloat16* ap = A + tq * 32;
        const __hip_bfloat16* bp = Bt + tq * 32;
#pragma unroll
        for (int i = 0; i < 2; i++) gload_lds16(ap + aOff[i], asb + i * 2048 + sdst);
#pragma unroll
        for (int i = 0; i < 4; i++) gload_lds16(bp + bOff[i], bsb + i * 2048 + sdst);
    };

    const int pSw = (l16 >> 1) & 3;
    f32x4 acc[4][8] = {};
    const int nt = K >> 5;

    stage(As[0], Bs[0], 0);
    stage(As[1], Bs[1], 1);
    stage(As[2], Bs[2], 2);
    wait_vm<2 * SL>();
    __builtin_amdgcn_s_barrier();
    __builtin_amdgcn_sched_barrier(0);

    for (int t = 0; t < nt; t += 3) {
#pragma unroll
        for (int u = 0; u < 3; u++) {
            const int tc = t + u;
            bf16x8 af[4], bfr[8];
#pragma unroll
            for (int mi = 0; mi < 4; mi++)
                af[mi] = *(const bf16x8*)&As[u][(wm + mi * 16 + l16) * 32 + ((g ^ pSw) << 3)];
#pragma unroll
            for (int ni = 0; ni < 8; ni++)
                bfr[ni] = *(const bf16x8*)&Bs[u][(wn + ni * 16 + l16) * 32 + ((g ^ pSw) << 3)];
#pragma unroll
            for (int mi = 0; mi < 4; mi++)
#pragma unroll
                for (int ni = 0; ni < 8; ni++)
                    acc[mi][ni] = __builtin_amdgcn_mfma_f32_16x16x32_bf16(af[mi], bfr[ni], acc[mi][ni], 0, 0, 0);

            asm volatile("s_waitcnt lgkmcnt(0)" ::: "memory");
            __builtin_amdgcn_sched_barrier(0);
            __builtin_amdgcn_s_barrier();
            __builtin_amdgcn_sched_barrier(0);

            if (tc + 3 < nt) stage(As[u], Bs[u], tc + 3);
            if (tc + 1 < nt) {
                if (tc + 4 <= nt)      wait_vm<2 * SL>();
                else if (tc + 3 == nt) wait_vm<SL>();
                else                   wait_vm<0>();
                __builtin_amdgcn_s_barrier();
                __builtin_amdgcn_sched_barrier(0);
            }
        }
    }

    // coalesced epilogue via per-wave LDS transpose (rows padded to 136 elems)
    __hip_bfloat16* scr = &As[0][0] + wid * (16 * 136);
#pragma unroll
    for (int mi = 0; mi < 4; mi++) {
#pragma unroll
        for (int ni = 0; ni < 8; ni++) {
            float bval = 0.0f;
            if (BIAS) bval = bias[bn + wn + ni * 16 + l16];
#pragma unroll
            for (int r = 0; r < 4; r++) {
                float v = acc[mi][ni][r] + bval;
                if (GELU) v = 0.5f * v * (1.0f + erff(v * 0.70710678118654752f));
                scr[(4 * g + r) * 136 + ni * 16 + l16] = __float2bfloat16(v);
            }
        }
        asm volatile("s_waitcnt lgkmcnt(0)" ::: "memory");
        __builtin_amdgcn_sched_barrier(0);
#pragma unroll
        for (int q2 = 0; q2 < 4; q2++) {
            int idx = q2 * 64 + lane;
            int row16 = idx >> 4, ch = idx & 15;
            bf16x8 vv = *(const bf16x8*)&scr[row16 * 136 + ch * 8];
            int grow = bm + wm + mi * 16 + row16;
            *(int4*)&Cb[(size_t)grow * N + bn + wn + ch * 8] = *(int4*)&vv;
        }
        asm volatile("s_waitcnt lgkmcnt(0)" ::: "memory");
        __builtin_amdgcn_sched_barrier(0);
    }
}

// ---------------- MFMA flash attention: softmax(q@k^T*scale + bias) @ v ----------------
__global__ __launch_bounds__(256) void attn_kernel(const __hip_bfloat16* __restrict__ qkvb,
                                                   const float* __restrict__ bias,   // [12][576][576] this layer
                                                   unsigned short* __restrict__ o)   // bf16 [4608][768]
{
    const int seq = (blockIdx.x & 7) * 108 + (blockIdx.x >> 3);
    const int bb = seq & 7, qt = (seq >> 3) % 9, h = seq / 72;
    const int q0 = qt * 64;
    const int tid = threadIdx.x;
    const int wq = tid >> 6, lane = tid & 63, g = lane >> 4, l16 = lane & 15;

    __shared__ __align__(16) unsigned short Qs[64 * 72];
    __shared__ __align__(16) unsigned short Ks[64 * 72];
    __shared__ __align__(16) unsigned short Vt[64 * 72];
    __shared__ __align__(16) unsigned short Ps[4][16 * 72];

    {
        int r = tid >> 2, cb = (tid & 3) * 16;
        const int4* s4 = (const int4*)&qkvb[(size_t)(bb * 576 + q0 + r) * 2304 + h * 64 + cb];
        int4* d4 = (int4*)&Qs[r * 72 + cb];
        d4[0] = s4[0]; d4[1] = s4[1];
    }
    __syncthreads();
    bf16x8 qf0 = *(const bf16x8*)&Qs[(wq * 16 + l16) * 72 + g * 8];
    bf16x8 qf1 = *(const bf16x8*)&Qs[(wq * 16 + l16) * 72 + 32 + g * 8];

    float m_r[4] = {-1e30f, -1e30f, -1e30f, -1e30f};
    float l_r[4] = {0.f, 0.f, 0.f, 0.f};
    f32x4 oa[4] = {};
    const float* bias_h = bias + (size_t)h * 576 * 576;
    const float scale = 0.125f;

    for (int kt = 0; kt < 576; kt += 64) {
        {
            int r = tid >> 2, cb = (tid & 3) * 16;
            const int4* s4 = (const int4*)&qkvb[(size_t)(bb * 576 + kt + r) * 2304 + 768 + h * 64 + cb];
            int4* d4 = (int4*)&Ks[r * 72 + cb];
            d4[0] = s4[0]; d4[1] = s4[1];
            int key = tid & 63, d0 = (tid >> 6) * 16;
            const unsigned short* vs = (const unsigned short*)&qkvb[(size_t)(bb * 576 + kt + key) * 2304 + 1536 + h * 64 + d0];
            bf16x8 v0 = *(const bf16x8*)vs;
            bf16x8 v1 = *(const bf16x8*)(vs + 8);
#pragma unroll
            for (int e = 0; e < 8; e++) {
                Vt[(d0 + e) * 72 + key] = (unsigned short)v0[e];
                Vt[(d0 + 8 + e) * 72 + key] = (unsigned short)v1[e];
            }
        }
        __syncthreads();

        float bl[4][4];
#pragma unroll
        for (int kc = 0; kc < 4; kc++)
#pragma unroll
            for (int r = 0; r < 4; r++) {
                int q = q0 + wq * 16 + 4 * g + r;
                bl[kc][r] = bias_h[(size_t)q * 576 + kt + kc * 16 + l16];
            }

        f32x4 sc[4] = {};
        __builtin_amdgcn_s_setprio(1);
#pragma unroll
        for (int kc = 0; kc < 4; kc++) {
            bf16x8 kf0 = *(const bf16x8*)&Ks[(kc * 16 + l16) * 72 + g * 8];
            bf16x8 kf1 = *(const bf16x8*)&Ks[(kc * 16 + l16) * 72 + 32 + g * 8];
            sc[kc] = __builtin_amdgcn_mfma_f32_16x16x32_bf16(qf0, kf0, sc[kc], 0, 0, 0);
            sc[kc] = __builtin_amdgcn_mfma_f32_16x16x32_bf16(qf1, kf1, sc[kc], 0, 0, 0);
        }
        __builtin_amdgcn_s_setprio(0);

        float sv[4][4], mt[4] = {-1e30f, -1e30f, -1e30f, -1e30f};
#pragma unroll
        for (int kc = 0; kc < 4; kc++)
#pragma unroll
            for (int r = 0; r < 4; r++) {
                float s = sc[kc][r] * scale + bl[kc][r];
                sv[kc][r] = s;
                mt[r] = fmaxf(mt[r], s);
            }
#pragma unroll
        for (int r = 0; r < 4; r++)
#pragma unroll
            for (int m = 1; m < 16; m <<= 1) mt[r] = fmaxf(mt[r], __shfl_xor(mt[r], m));

        float sf[4];
#pragma unroll
        for (int r = 0; r < 4; r++) {
            float mn = fmaxf(m_r[r], mt[r]);
            sf[r] = __expf(m_r[r] - mn);
            m_r[r] = mn;
        }
        float rs[4] = {0.f, 0.f, 0.f, 0.f};
#pragma unroll
        for (int kc = 0; kc < 4; kc++)
#pragma unroll
            for (int r = 0; r < 4; r++) {
                float p = __expf(sv[kc][r] - m_r[r]);
                rs[r] += p;
                Ps[wq][(4 * g + r) * 72 + kc * 16 + l16] = f2bf_bits(p);
            }
#pragma unroll
        for (int r = 0; r < 4; r++) {
#pragma unroll
            for (int m = 1; m < 16; m <<= 1) rs[r] += __shfl_xor(rs[r], m);
            l_r[r] = l_r[r] * sf[r] + rs[r];
        }
#pragma unroll
        for (int dt = 0; dt < 4; dt++)
#pragma unroll
            for (int r = 0; r < 4; r++) oa[dt][r] *= sf[r];

        asm volatile("s_waitcnt lgkmcnt(0)" ::: "memory");

        __builtin_amdgcn_s_setprio(1);
#pragma unroll
        for (int s = 0; s < 2; s++) {
            bf16x8 pf = *(const bf16x8*)&Ps[wq][l16 * 72 + s * 32 + g * 8];
#pragma unroll
            for (int dt = 0; dt < 4; dt++) {
                bf16x8 vf = *(const bf16x8*)&Vt[(dt * 16 + l16) * 72 + s * 32 + g * 8];
                oa[dt] = __builtin_amdgcn_mfma_f32_16x16x32_bf16(pf, vf, oa[dt], 0, 0, 0);
            }
        }
        __builtin_amdgcn_s_setprio(0);
        __syncthreads();
    }

#pragma unroll
    for (int dt = 0; dt < 4; dt++)
#pragma unroll
        for (int r = 0; r < 4; r++) {
            int q = q0 + wq * 16 + 4 * g + r;
            float v = oa[dt][r] / l_r[r];
            o[(size_t)(bb * 576 + q) * 768 + h * 64 + dt * 16 + l16] = f2bf_bits(v);
        }
}

// ---------------- mean pool over 576 tokens (bf16 in) ----------------
__global__ __launch_bounds__(256) void pool_kernel(const __hip_bfloat16* __restrict__ tok,
                                                   float* __restrict__ pooled)
{
    int d = blockIdx.x * 256 + threadIdx.x;
    int b = blockIdx.y;
    float s = 0.0f;
    for (int n = 0; n < 576; n++) s += __bfloat162float(tok[(size_t)(b * 576 + n) * 768 + d]);
    pooled[b * 768 + d] = s * (1.0f / 576.0f);
}

// ---------------- classifier head ----------------
__global__ __launch_bounds__(256) void head_kernel(const float* __restrict__ lnp,
                                                   const float* __restrict__ w,
                                                   const float* __restrict__ bh,
                                                   float* __restrict__ out)
{
    int c = blockIdx.x * 256 + threadIdx.x;
    int b = blockIdx.y;
    if (c >= 1000) return;
    float s = bh[c];
    for (int d = 0; d < 768; d++) s += lnp[b * 768 + d] * w[(size_t)d * 1000 + c];
    out[b * 1000 + c] = s;
}

extern "C" void kernel_launch(void* const* d_in, const int* in_sizes, int n_in,
                              void* d_out, int out_size, void* d_ws, size_t ws_size,
                              hipStream_t stream)
{
    const float* x = (const float*)d_in[0];
    const float* patch_w = (const float*)d_in[1];
    const float* patch_b = (const float*)d_in[2];
    const float* ln1_g = (const float*)d_in[3];
    const float* ln1_b = (const float*)d_in[4];
    const float* w_qkv = (const float*)d_in[5];
    const float* bias_att = (const float*)d_in[6];
    const float* w_out = (const float*)d_in[7];
    const float* ln2_g = (const float*)d_in[8];
    const float* ln2_b = (const float*)d_in[9];
    const float* w1 = (const float*)d_in[10];
    const float* b1 = (const float*)d_in[11];
    const float* w2 = (const float*)d_in[12];
    const float* b2 = (const float*)d_in[13];
    const float* lnh_g = (const float*)d_in[14];
    const float* lnh_b = (const float*)d_in[15];
    const float* w_head = (const float*)d_in[16];
    const float* b_head = (const float*)d_in[17];
    float* out = (float*)d_out;

    char* ws = (char*)d_ws;
    __hip_bfloat16* tok = (__hip_bfloat16*)(ws + 0);             // 4608*768 bf16
    __hip_bfloat16* qkv_bf = (__hip_bfloat16*)(ws + 14155776);   // 4608*2304 bf16
    float* pooled = (float*)(ws + 56623104);
    float* pooledln = (float*)(ws + 56647680);
    __hip_bfloat16* patches = (__hip_bfloat16*)(ws + 56672256);  // 4608*1536 bf16
    __hip_bfloat16* lw = patches;                                // layer weights reuse after patch GEMM
    __hip_bfloat16* h_bf = (__hip_bfloat16*)(ws + 70828032);
    __hip_bfloat16* o_bf = (__hip_bfloat16*)(ws + 77905920);
    __hip_bfloat16* hid_bf = (__hip_bfloat16*)(ws + 84983808);
    __hip_bfloat16* wbuf = (__hip_bfloat16*)(ws + 113295360);    // patch weight 768*1536 bf16

    // patch embedding
    patchify_kernel<<<3456, 256, 0, stream>>>(x, (unsigned short*)patches);
    convT_patch_kernel<<<dim3(24, 48), 256, 0, stream>>>(patch_w, wbuf);
    gemm_bt_kernel<true, false><<<432, 256, 0, stream>>>(
        patches, wbuf, patch_b, nullptr, tok, 4608, 768, 1536, 6);

    for (int l = 0; l < 4; l++) {
        convT4_kernel<<<6912, 256, 0, stream>>>(
            w_qkv + (size_t)l * 768 * 2304, w_out + (size_t)l * 768 * 768,
            w1 + (size_t)l * 768 * 3072, w2 + (size_t)l * 3072 * 768, lw);
        // attn sub-block
        ln_kernel<__hip_bfloat16, __hip_bfloat16><<<4608, 256, 0, stream>>>(
            tok, ln1_g + l * 768, ln1_b + l * 768, h_bf);
        gemm_wide_kernel<false, false><<<324, 256, 0, stream>>>(
            h_bf, lw, nullptr, qkv_bf, 4608, 2304, 768, 9);
        attn_kernel<<<864, 256, 0, stream>>>(
            qkv_bf, bias_att + (size_t)l * 12 * 576 * 576, (unsigned short*)o_bf);
        gemm_bt_kernel<false, true><<<432, 256, 0, stream>>>(
            o_bf, lw + 1769472, nullptr, tok, tok, 4608, 768, 768, 6);
        // mlp sub-block
        ln_kernel<__hip_bfloat16, __hip_bfloat16><<<4608, 256, 0, stream>>>(
            tok, ln2_g + l * 768, ln2_b + l * 768, h_bf);
        gemm_wide_kernel<true, true><<<432, 256, 0, stream>>>(
            h_bf, lw + 2359296, b1 + l * 3072, hid_bf, 4608, 3072, 768, 12);
        gemm_bt_kernel<true, true><<<432, 256, 0, stream>>>(
            hid_bf, lw + 4718592, b2 + l * 768, tok, tok, 4608, 768, 3072, 6);
    }

    pool_kernel<<<dim3(3, 8), 256, 0, stream>>>(tok, pooled);
    ln_kernel<float, float><<<8, 256, 0, stream>>>(pooled, lnh_g, lnh_b, pooledln);
    head_kernel<<<dim3(4, 8), 256, 0, stream>>>(pooledln, w_head, b_head, out);
}

// Round 9
// 835.715 us; speedup vs baseline: 1.1035x; 1.0116x over previous
//
#include <hip/hip_runtime.h>
#include <hip/hip_bf16.h>

typedef __attribute__((ext_vector_type(8))) short bf16x8;
typedef __attribute__((ext_vector_type(4))) float f32x4;

#define DEVI __device__ __forceinline__

DEVI unsigned short f2bf_bits(float f) {
    __hip_bfloat16 h = __float2bfloat16(f);
    return *reinterpret_cast<unsigned short*>(&h);
}
DEVI float bfbits2f(unsigned short u) {
    __hip_bfloat16 h = *reinterpret_cast<__hip_bfloat16*>(&u);
    return __bfloat162float(h);
}

// async global->LDS, 16B per lane. LDS dest is wave-uniform base + lane*16 (linear).
DEVI void gload_lds16(const void* g, void* lds) {
    __builtin_amdgcn_global_load_lds(
        (const __attribute__((address_space(1))) unsigned int*)g,
        (__attribute__((address_space(3))) unsigned int*)lds, 16, 0, 0);
}

template <int N> DEVI void wait_vm() {
    if constexpr (N == 0) asm volatile("s_waitcnt vmcnt(0)" ::: "memory");
    else if constexpr (N == 4) asm volatile("s_waitcnt vmcnt(4)" ::: "memory");
    else if constexpr (N == 6) asm volatile("s_waitcnt vmcnt(6)" ::: "memory");
    else if constexpr (N == 12) asm volatile("s_waitcnt vmcnt(12)" ::: "memory");
    __builtin_amdgcn_sched_barrier(0);
}
DEVI void lgkm0() {
    asm volatile("s_waitcnt lgkmcnt(0)" ::: "memory");
    __builtin_amdgcn_sched_barrier(0);
}

// bijective XCD chunking (m204) + group-of-4-rows locality (requires nrow%4==0)
DEVI int2 remap2d(int bid, int total, int gx) {
    int q = total >> 3, r = total & 7, x = bid & 7, l = bid >> 3;
    int seq = (x < r ? x * (q + 1) : r * (q + 1) + (x - r) * q) + l;
    int g4 = seq / (4 * gx);
    int rem = seq - g4 * 4 * gx;
    return {g4 * 4 + (rem & 3), rem >> 2};   // (by, bx)
}
// group-of-2 variant (requires nrow%2==0) — used by 256-tile kernels (nrow=18)
DEVI int2 remap2d_g2(int bid, int total, int gx) {
    int q = total >> 3, r = total & 7, x = bid & 7, l = bid >> 3;
    int seq = (x < r ? x * (q + 1) : r * (q + 1) + (x - r) * q) + l;
    int g2 = seq / (2 * gx);
    int rem = seq - g2 * 2 * gx;
    return {g2 * 2 + (rem & 1), rem >> 1};
}

// ---------------- patchify: x[B,C,384,384] -> patches bf16 [4608][1536] (c-major patch dim) ----
__global__ __launch_bounds__(256) void patchify_kernel(const float* __restrict__ x,
                                                       unsigned short* __restrict__ patches)
{
    size_t t8 = (size_t)blockIdx.x * 256 + threadIdx.x;   // 884,736 threads, 8 floats each
    int jq = (int)(t8 % 48);
    size_t t = t8 / 48;
    int r = (int)(t % 384); t /= 384;
    int c = (int)(t % 6);
    int b = (int)(t / 6);
    int j = jq * 8;
    int gh = r >> 4, p1 = r & 15, gw = j >> 4, p2 = j & 15;
    int prow = b * 576 + gh * 24 + gw;
    int pcol = c * 256 + p1 * 16 + p2;
    const float* src = x + ((((size_t)b * 6 + c) * 384 + r) * 384 + j);
    float4 v0 = ((const float4*)src)[0];
    float4 v1 = ((const float4*)src)[1];
    ushort u[8] = { f2bf_bits(v0.x), f2bf_bits(v0.y), f2bf_bits(v0.z), f2bf_bits(v0.w),
                    f2bf_bits(v1.x), f2bf_bits(v1.y), f2bf_bits(v1.z), f2bf_bits(v1.w) };
    *(int4*)&patches[(size_t)prow * 1536 + pcol] = *(int4*)u;
}

// ---------------- patch-weight convert: W f32 [1536][768] -> Wt bf16 [768][1536'] (k-permuted) --
__global__ __launch_bounds__(256) void convT_patch_kernel(const float* __restrict__ W,
                                                          __hip_bfloat16* __restrict__ Wt)
{
    __shared__ float tile[32][33];
    int n0 = blockIdx.x * 32, kp0 = blockIdx.y * 32;
    int tx = threadIdx.x & 31, ty = threadIdx.x >> 5;
#pragma unroll
    for (int i = 0; i < 4; i++) {
        int kp = kp0 + ty + 8 * i;
        int k = (kp & 255) * 6 + (kp >> 8);   // inverse of k' = c*256 + pp
        tile[ty + 8 * i][tx] = W[(size_t)k * 768 + n0 + tx];
    }
    __syncthreads();
#pragma unroll
    for (int i = 0; i < 4; i++)
        Wt[(size_t)(n0 + ty + 8 * i) * 1536 + kp0 + tx] = __float2bfloat16(tile[tx][ty + 8 * i]);
}

// ---------------- weight convert + transpose: W f32 [K][N] -> Wt bf16 [N][K] ----------------
DEVI void convT_body(const float* __restrict__ W, __hip_bfloat16* __restrict__ Wt,
                     int K, int N, int k0, int n0, int tid)
{
    __shared__ float tile[32][33];
    int tx = tid & 31, ty = tid >> 5;
#pragma unroll
    for (int i = 0; i < 4; i++)
        tile[ty + 8 * i][tx] = W[(size_t)(k0 + ty + 8 * i) * N + n0 + tx];
    __syncthreads();
#pragma unroll
    for (int i = 0; i < 4; i++)
        Wt[(size_t)(n0 + ty + 8 * i) * K + k0 + tx] = __float2bfloat16(tile[tx][ty + 8 * i]);
}

__global__ __launch_bounds__(256) void convT4_kernel(const float* __restrict__ wqkv,
                                                     const float* __restrict__ wout,
                                                     const float* __restrict__ w1,
                                                     const float* __restrict__ w2,
                                                     __hip_bfloat16* __restrict__ dst)
{
    int bt = blockIdx.x;
    const float* W; __hip_bfloat16* Wt; int K, N, lt;
    if (bt < 1728)      { W = wqkv; K = 768;  N = 2304; lt = bt;        Wt = dst; }
    else if (bt < 2304) { W = wout; K = 768;  N = 768;  lt = bt - 1728; Wt = dst + 1769472; }
    else if (bt < 4608) { W = w1;   K = 768;  N = 3072; lt = bt - 2304; Wt = dst + 2359296; }
    else                { W = w2;   K = 3072; N = 768;  lt = bt - 4608; Wt = dst + 4718592; }
    int tn = N >> 5;
    convT_body(W, Wt, K, N, (lt / tn) * 32, (lt % tn) * 32, threadIdx.x);
}

// ---------------- layernorm over 768 cols (templated in/out) ----------------
DEVI float ld_ln(const float* p) { return *p; }
DEVI float ld_ln(const __hip_bfloat16* p) { return __bfloat162float(*p); }
DEVI void st_ln(float* p, float v) { *p = v; }
DEVI void st_ln(__hip_bfloat16* p, float v) { *p = __float2bfloat16(v); }

template <typename InT, typename OutT>
__global__ __launch_bounds__(256) void ln_kernel(const InT* __restrict__ x,
                                                 const float* __restrict__ g,
                                                 const float* __restrict__ b,
                                                 OutT* __restrict__ out)
{
    int row = blockIdx.x, tid = threadIdx.x;
    const InT* xr = x + (size_t)row * 768;
    float v0 = ld_ln(&xr[tid]), v1 = ld_ln(&xr[tid + 256]), v2 = ld_ln(&xr[tid + 512]);
    float s = v0 + v1 + v2;
    float s2 = v0 * v0 + v1 * v1 + v2 * v2;
#pragma unroll
    for (int m = 32; m >= 1; m >>= 1) { s += __shfl_xor(s, m); s2 += __shfl_xor(s2, m); }
    __shared__ float red[8];
    int w = tid >> 6;
    if ((tid & 63) == 0) { red[w] = s; red[4 + w] = s2; }
    __syncthreads();
    s = red[0] + red[1] + red[2] + red[3];
    s2 = red[4] + red[5] + red[6] + red[7];
    float mean = s * (1.0f / 768.0f);
    float var = s2 * (1.0f / 768.0f) - mean * mean;
    float rstd = rsqrtf(var + 1e-5f);
    OutT* orow = out + (size_t)row * 768;
    st_ln(&orow[tid], (v0 - mean) * rstd * g[tid] + b[tid]);
    st_ln(&orow[tid + 256], (v1 - mean) * rstd * g[tid + 256] + b[tid + 256]);
    st_ln(&orow[tid + 512], (v2 - mean) * rstd * g[tid + 512] + b[tid + 512]);
}

// ================= 256x256 8-phase GEMM (m201 template port): C = A @ Bt^T =================
// BK=64 (2 k-halves of 32), 8 waves (2M x 4N), 512 threads, 2 LDS buffers (128 KiB).
// LDS layout per operand: [buf][kh][256 rows][32 elems]; chunk swizzle phys = logical ^
// ((row>>1)&3), applied on the per-lane GLOBAL source (gload dest linear) and on ds_read.
// Per K-tile t (buf b=t&1), 4 phases; stage order: p1:(t+1).A-kh1, p2:(t+1).B-kh1 (into b^1),
// p3:(t+2).A-kh0, p4:(t+2).B-kh0 (into b — regions free after p1/p2 resp.).
// Single vmcnt(4) per tile at p4: retires all 8 loads of tile t+1, keeps 2 half-tiles in flight.
template <bool BIAS, bool GELU>
__global__ __launch_bounds__(512, 2) void gemm_8ph_kernel(
    const __hip_bfloat16* __restrict__ A,
    const __hip_bfloat16* __restrict__ Bt,
    const float* __restrict__ bias,
    __hip_bfloat16* __restrict__ Cb,
    int M, int N, int K, int gx)
{
    __shared__ __align__(16) __hip_bfloat16 AsF[32768];   // [2][2][256][32]
    __shared__ __align__(16) __hip_bfloat16 BsF[32768];
    const int tid = threadIdx.x;
    const int wid = tid >> 6, lane = tid & 63;
    const int g = lane >> 4, l16 = lane & 15;
    const int wmh = wid >> 2, wnn = wid & 3;          // M-half (128 rows), N-quarter (64 cols)

    int2 bc = remap2d_g2(blockIdx.x, gridDim.x, gx);
    const int bm = bc.x * 256, bn = bc.y * 256;

    // staging geometry: per gload instr i, thread covers row = i*128 + (tid>>2), phys chunk tid&3
    const int srow = tid >> 2;
    size_t aS[2], bS[2];
#pragma unroll
    for (int i = 0; i < 2; i++) {
        int row = i * 128 + srow;
        int lc = (tid & 3) ^ ((row >> 1) & 3);
        aS[i] = (size_t)(bm + row) * K + lc * 8;
        bS[i] = (size_t)(bn + row) * K + lc * 8;
    }
    auto stageA = [&](int buf, int kh, int tq) {
        const __hip_bfloat16* ap = A + (size_t)tq * 64 + kh * 32;
        __hip_bfloat16* dst = AsF + (buf * 2 + kh) * 8192;
        gload_lds16(ap + aS[0], dst + tid * 8);
        gload_lds16(ap + aS[1], dst + 4096 + tid * 8);
    };
    auto stageB = [&](int buf, int kh, int tq) {
        const __hip_bfloat16* bp = Bt + (size_t)tq * 64 + kh * 32;
        __hip_bfloat16* dst = BsF + (buf * 2 + kh) * 8192;
        gload_lds16(bp + bS[0], dst + tid * 8);
        gload_lds16(bp + bS[1], dst + 4096 + tid * 8);
    };

    // fragment read offsets (within a [256][32] kh-half), chunk-swizzled
    const int csw = (l16 >> 1) & 3;
    const int rdo = (g ^ csw) << 3;
    const int aBase = (wmh * 128 + l16) * 32 + rdo;   // + mi*512 + (buf*2+kh)*8192
    const int bBase = (wnn * 64 + l16) * 32 + rdo;    // + ni*512 + (buf*2+kh)*8192

    f32x4 acc[8][4] = {};
    const int nt = K >> 6;   // 12 for K=768 (>= 2 assumed)

    // prologue: tile0 all 4 halves + tile1 kh0 pair; wait tile0 landed (4 instrs in flight)
    stageA(0, 0, 0); stageB(0, 0, 0); stageA(0, 1, 0); stageB(0, 1, 0);
    stageA(1, 0, 1); stageB(1, 0, 1);
    wait_vm<4>();
    __builtin_amdgcn_s_barrier();
    __builtin_amdgcn_sched_barrier(0);

    bf16x8 af[8], bf2[2];
    for (int t = 0; t < nt; t++) {
        const int b = t & 1;
        const int k0 = (b * 2 + 0) * 8192, k1 = (b * 2 + 1) * 8192;

        // ---- phase 1: kh0, N-frags 0,1 (reads A kh0 all 8 + B kh0 0,1)
#pragma unroll
        for (int mi = 0; mi < 8; mi++) af[mi] = *(const bf16x8*)&AsF[k0 + aBase + mi * 512];
        bf2[0] = *(const bf16x8*)&BsF[k0 + bBase + 0 * 512];
        bf2[1] = *(const bf16x8*)&BsF[k0 + bBase + 1 * 512];
        if (t + 1 < nt) stageA(b ^ 1, 1, t + 1);
        __builtin_amdgcn_s_barrier(); lgkm0();
        __builtin_amdgcn_s_setprio(1);
#pragma unroll
        for (int mi = 0; mi < 8; mi++) {
            acc[mi][0] = __builtin_amdgcn_mfma_f32_16x16x32_bf16(af[mi], bf2[0], acc[mi][0], 0, 0, 0);
            acc[mi][1] = __builtin_amdgcn_mfma_f32_16x16x32_bf16(af[mi], bf2[1], acc[mi][1], 0, 0, 0);
        }
        __builtin_amdgcn_s_setprio(0);
        __builtin_amdgcn_s_barrier();

        // ---- phase 2: kh0, N-frags 2,3 (reuse af)
        bf2[0] = *(const bf16x8*)&BsF[k0 + bBase + 2 * 512];
        bf2[1] = *(const bf16x8*)&BsF[k0 + bBase + 3 * 512];
        if (t + 1 < nt) stageB(b ^ 1, 1, t + 1);
        __builtin_amdgcn_s_barrier(); lgkm0();
        __builtin_amdgcn_s_setprio(1);
#pragma unroll
        for (int mi = 0; mi < 8; mi++) {
            acc[mi][2] = __builtin_amdgcn_mfma_f32_16x16x32_bf16(af[mi], bf2[0], acc[mi][2], 0, 0, 0);
            acc[mi][3] = __builtin_amdgcn_mfma_f32_16x16x32_bf16(af[mi], bf2[1], acc[mi][3], 0, 0, 0);
        }
        __builtin_amdgcn_s_setprio(0);
        __builtin_amdgcn_s_barrier();

        // ---- phase 3: kh1, N-frags 0,1
#pragma unroll
        for (int mi = 0; mi < 8; mi++) af[mi] = *(const bf16x8*)&AsF[k1 + aBase + mi * 512];
        bf2[0] = *(const bf16x8*)&BsF[k1 + bBase + 0 * 512];
        bf2[1] = *(const bf16x8*)&BsF[k1 + bBase + 1 * 512];
        if (t + 2 < nt) stageA(b, 0, t + 2);
        __builtin_amdgcn_s_barrier(); lgkm0();
        __builtin_amdgcn_s_setprio(1);
#pragma unroll
        for (int mi = 0; mi < 8; mi++) {
            acc[mi][0] = __builtin_amdgcn_mfma_f32_16x16x32_bf16(af[mi], bf2[0], acc[mi][0], 0, 0, 0);
            acc[mi][1] = __builtin_amdgcn_mfma_f32_16x16x32_bf16(af[mi], bf2[1], acc[mi][1], 0, 0, 0);
        }
        __builtin_amdgcn_s_setprio(0);
        __builtin_amdgcn_s_barrier();

        // ---- phase 4: kh1, N-frags 2,3 + per-tile counted vmcnt
        bf2[0] = *(const bf16x8*)&BsF[k1 + bBase + 2 * 512];
        bf2[1] = *(const bf16x8*)&BsF[k1 + bBase + 3 * 512];
        if (t + 2 < nt) stageB(b, 0, t + 2);
        __builtin_amdgcn_s_barrier(); lgkm0();
        __builtin_amdgcn_s_setprio(1);
#pragma unroll
        for (int mi = 0; mi < 8; mi++) {
            acc[mi][2] = __builtin_amdgcn_mfma_f32_16x16x32_bf16(af[mi], bf2[0], acc[mi][2], 0, 0, 0);
            acc[mi][3] = __builtin_amdgcn_mfma_f32_16x16x32_bf16(af[mi], bf2[1], acc[mi][3], 0, 0, 0);
        }
        __builtin_amdgcn_s_setprio(0);
        if (t + 2 < nt) wait_vm<4>();    // all of tile t+1 landed; tile t+2's kh0 pair in flight
        else            wait_vm<0>();    // tail drain
        __builtin_amdgcn_s_barrier();
        __builtin_amdgcn_sched_barrier(0);
    }

    // epilogue: per-wave LDS transpose (private 16x72 region), coalesced 16B stores
    __hip_bfloat16* scr = AsF + wid * (16 * 72);
#pragma unroll
    for (int mi = 0; mi < 8; mi++) {
#pragma unroll
        for (int ni = 0; ni < 4; ni++) {
            float bval = 0.0f;
            if (BIAS) bval = bias[bn + wnn * 64 + ni * 16 + l16];
#pragma unroll
            for (int r = 0; r < 4; r++) {
                float v = acc[mi][ni][r] + bval;
                if (GELU) v = 0.5f * v * (1.0f + erff(v * 0.70710678118654752f));
                scr[(4 * g + r) * 72 + ni * 16 + l16] = __float2bfloat16(v);
            }
        }
        lgkm0();
#pragma unroll
        for (int q2 = 0; q2 < 2; q2++) {
            int idx = q2 * 64 + lane;
            int row16 = idx >> 3, ch = idx & 7;
            bf16x8 vv = *(const bf16x8*)&scr[row16 * 72 + ch * 8];
            int grow = bm + wmh * 128 + mi * 16 + row16;
            *(int4*)&Cb[(size_t)grow * N + bn + wnn * 64 + ch * 8] = *(int4*)&vv;
        }
        lgkm0();
    }
}

// ---------------- narrow GEMM: BM=64 x BN=128, BK=64, 3-deep counted-vmcnt, bf16 out ----------
template <bool BIAS, bool RESID>
__global__ __launch_bounds__(256, 2) void gemm_bt_kernel(
    const __hip_bfloat16* __restrict__ A,
    const __hip_bfloat16* __restrict__ Bt,
    const float* __restrict__ bias,
    const __hip_bfloat16* __restrict__ resid,
    __hip_bfloat16* __restrict__ Cb,
    int M, int N, int K, int gx)
{
    constexpr int BM = 64, SL = 6;
    __shared__ __align__(16) __hip_bfloat16 As[3][BM * 64];
    __shared__ __align__(16) __hip_bfloat16 Bs[3][128 * 64];
    const int tid = threadIdx.x;
    const int wid = tid >> 6, lane = tid & 63;
    const int g = lane >> 4, l16 = lane & 15;
    const int wm = (wid >> 1) * 32, wn = (wid & 1) * 64;

    int2 bc = remap2d(blockIdx.x, gridDim.x, gx);
    const int bm = bc.x * BM, bn = bc.y * 128;

    const int sr32 = tid >> 3, ci = tid & 7;
    const int cg = ci ^ (sr32 & 7);
    const int sdst = tid * 8;
    size_t aOff[2], bOff[4];
#pragma unroll
    for (int i = 0; i < 2; i++) aOff[i] = (size_t)(bm + i * 32 + sr32) * K + cg * 8;
#pragma unroll
    for (int i = 0; i < 4; i++) bOff[i] = (size_t)(bn + i * 32 + sr32) * K + cg * 8;

    auto stage = [&](__hip_bfloat16* asb, __hip_bfloat16* bsb, int tq) {
        const __hip_bfloat16* ap = A + tq * 64;
        const __hip_bfloat16* bp = Bt + tq * 64;
#pragma unroll
        for (int i = 0; i < 2; i++) gload_lds16(ap + aOff[i], asb + i * 2048 + sdst);
#pragma unroll
        for (int i = 0; i < 4; i++) gload_lds16(bp + bOff[i], bsb + i * 2048 + sdst);
    };

    f32x4 acc[2][4] = {};
    const int nt = K >> 6;

    stage(As[0], Bs[0], 0);
    stage(As[1], Bs[1], 1);
    stage(As[2], Bs[2], 2);
    wait_vm<12>();
    __builtin_amdgcn_s_barrier();
    __builtin_amdgcn_sched_barrier(0);

    for (int t = 0; t < nt; t += 3) {
#pragma unroll
        for (int u = 0; u < 3; u++) {
            const int tc = t + u;
            bf16x8 af[2][2], bfr[2][4];
#pragma unroll
            for (int s = 0; s < 2; s++) {
                const int cp = ((s * 4 + g) ^ (l16 & 7)) << 3;
#pragma unroll
                for (int mi = 0; mi < 2; mi++)
                    af[s][mi] = *(const bf16x8*)&As[u][(wm + mi * 16 + l16) * 64 + cp];
#pragma unroll
                for (int ni = 0; ni < 4; ni++)
                    bfr[s][ni] = *(const bf16x8*)&Bs[u][(wn + ni * 16 + l16) * 64 + cp];
            }
#pragma unroll
            for (int s = 0; s < 2; s++)
#pragma unroll
                for (int mi = 0; mi < 2; mi++)
#pragma unroll
                    for (int ni = 0; ni < 4; ni++)
                        acc[mi][ni] = __builtin_amdgcn_mfma_f32_16x16x32_bf16(af[s][mi], bfr[s][ni], acc[mi][ni], 0, 0, 0);

            lgkm0();
            __builtin_amdgcn_s_barrier();
            __builtin_amdgcn_sched_barrier(0);

            if (tc + 3 < nt) stage(As[u], Bs[u], tc + 3);
            if (tc + 1 < nt) {
                if (tc + 4 <= nt)      wait_vm<12>();
                else if (tc + 3 == nt) wait_vm<6>();
                else                   wait_vm<0>();
                __builtin_amdgcn_s_barrier();
                __builtin_amdgcn_sched_barrier(0);
            }
        }
    }

    __hip_bfloat16* scr = &As[0][0] + wid * (16 * 72);
#pragma unroll
    for (int mi = 0; mi < 2; mi++) {
#pragma unroll
        for (int ni = 0; ni < 4; ni++) {
            float bval = 0.0f;
            if (BIAS) bval = bias[bn + wn + ni * 16 + l16];
#pragma unroll
            for (int r = 0; r < 4; r++)
                scr[(4 * g + r) * 72 + ni * 16 + l16] = __float2bfloat16(acc[mi][ni][r] + bval);
        }
        lgkm0();
#pragma unroll
        for (int q2 = 0; q2 < 2; q2++) {
            int row16 = q2 * 8 + (lane >> 3), ch = lane & 7;
            bf16x8 vv = *(const bf16x8*)&scr[row16 * 72 + ch * 8];
            int grow = bm + wm + mi * 16 + row16;
            size_t off = (size_t)grow * N + bn + wn + ch * 8;
            if (RESID) {
                bf16x8 rv = *(const bf16x8*)&resid[off];
#pragma unroll
                for (int e = 0; e < 8; e++)
                    vv[e] = (short)f2bf_bits(bfbits2f((unsigned short)vv[e]) + bfbits2f((unsigned short)rv[e]));
            }
            *(int4*)&Cb[off] = *(int4*)&vv;
        }
        lgkm0();
    }
}

// ---------------- MFMA flash attention: softmax(q@k^T*scale + bias) @ v ----------------
__global__ __launch_bounds__(256) void attn_kernel(const __hip_bfloat16* __restrict__ qkvb,
                                                   const float* __restrict__ bias,   // [12][576][576] this layer
                                                   unsigned short* __restrict__ o)   // bf16 [4608][768]
{
    const int seq = (blockIdx.x & 7) * 108 + (blockIdx.x >> 3);
    const int bb = seq & 7, qt = (seq >> 3) % 9, h = seq / 72;
    const int q0 = qt * 64;
    const int tid = threadIdx.x;
    const int wq = tid >> 6, lane = tid & 63, g = lane >> 4, l16 = lane & 15;

    __shared__ __align__(16) unsigned short Qs[64 * 72];
    __shared__ __align__(16) unsigned short Ks[64 * 72];
    __shared__ __align__(16) unsigned short Vt[64 * 72];
    __shared__ __align__(16) unsigned short Ps[4][16 * 72];

    {
        int r = tid >> 2, cb = (tid & 3) * 16;
        const int4* s4 = (const int4*)&qkvb[(size_t)(bb * 576 + q0 + r) * 2304 + h * 64 + cb];
        int4* d4 = (int4*)&Qs[r * 72 + cb];
        d4[0] = s4[0]; d4[1] = s4[1];
    }
    __syncthreads();
    bf16x8 qf0 = *(const bf16x8*)&Qs[(wq * 16 + l16) * 72 + g * 8];
    bf16x8 qf1 = *(const bf16x8*)&Qs[(wq * 16 + l16) * 72 + 32 + g * 8];

    float m_r[4] = {-1e30f, -1e30f, -1e30f, -1e30f};
    float l_r[4] = {0.f, 0.f, 0.f, 0.f};
    f32x4 oa[4] = {};
    const float* bias_h = bias + (size_t)h * 576 * 576;
    const float scale = 0.125f;

    for (int kt = 0; kt < 576; kt += 64) {
        {
            int r = tid >> 2, cb = (tid & 3) * 16;
            const int4* s4 = (const int4*)&qkvb[(size_t)(bb * 576 + kt + r) * 2304 + 768 + h * 64 + cb];
            int4* d4 = (int4*)&Ks[r * 72 + cb];
            d4[0] = s4[0]; d4[1] = s4[1];
            int key = tid & 63, d0 = (tid >> 6) * 16;
            const unsigned short* vs = (const unsigned short*)&qkvb[(size_t)(bb * 576 + kt + key) * 2304 + 1536 + h * 64 + d0];
            bf16x8 v0 = *(const bf16x8*)vs;
            bf16x8 v1 = *(const bf16x8*)(vs + 8);
#pragma unroll
            for (int e = 0; e < 8; e++) {
                Vt[(d0 + e) * 72 + key] = (unsigned short)v0[e];
                Vt[(d0 + 8 + e) * 72 + key] = (unsigned short)v1[e];
            }
        }
        __syncthreads();

        float bl[4][4];
#pragma unroll
        for (int kc = 0; kc < 4; kc++)
#pragma unroll
            for (int r = 0; r < 4; r++) {
                int q = q0 + wq * 16 + 4 * g + r;
                bl[kc][r] = bias_h[(size_t)q * 576 + kt + kc * 16 + l16];
            }

        f32x4 sc[4] = {};
        __builtin_amdgcn_s_setprio(1);
#pragma unroll
        for (int kc = 0; kc < 4; kc++) {
            bf16x8 kf0 = *(const bf16x8*)&Ks[(kc * 16 + l16) * 72 + g * 8];
            bf16x8 kf1 = *(const bf16x8*)&Ks[(kc * 16 + l16) * 72 + 32 + g * 8];
            sc[kc] = __builtin_amdgcn_mfma_f32_16x16x32_bf16(qf0, kf0, sc[kc], 0, 0, 0);
            sc[kc] = __builtin_amdgcn_mfma_f32_16x16x32_bf16(qf1, kf1, sc[kc], 0, 0, 0);
        }
        __builtin_amdgcn_s_setprio(0);

        float sv[4][4], mt[4] = {-1e30f, -1e30f, -1e30f, -1e30f};
#pragma unroll
        for (int kc = 0; kc < 4; kc++)
#pragma unroll
            for (int r = 0; r < 4; r++) {
                float s = sc[kc][r] * scale + bl[kc][r];
                sv[kc][r] = s;
                mt[r] = fmaxf(mt[r], s);
            }
#pragma unroll
        for (int r = 0; r < 4; r++)
#pragma unroll
            for (int m = 1; m < 16; m <<= 1) mt[r] = fmaxf(mt[r], __shfl_xor(mt[r], m));

        float sf[4];
#pragma unroll
        for (int r = 0; r < 4; r++) {
            float mn = fmaxf(m_r[r], mt[r]);
            sf[r] = __expf(m_r[r] - mn);
            m_r[r] = mn;
        }
        float rs[4] = {0.f, 0.f, 0.f, 0.f};
#pragma unroll
        for (int kc = 0; kc < 4; kc++)
#pragma unroll
            for (int r = 0; r < 4; r++) {
                float p = __expf(sv[kc][r] - m_r[r]);
                rs[r] += p;
                Ps[wq][(4 * g + r) * 72 + kc * 16 + l16] = f2bf_bits(p);
            }
#pragma unroll
        for (int r = 0; r < 4; r++) {
#pragma unroll
            for (int m = 1; m < 16; m <<= 1) rs[r] += __shfl_xor(rs[r], m);
            l_r[r] = l_r[r] * sf[r] + rs[r];
        }
#pragma unroll
        for (int dt = 0; dt < 4; dt++)
#pragma unroll
            for (int r = 0; r < 4; r++) oa[dt][r] *= sf[r];

        asm volatile("s_waitcnt lgkmcnt(0)" ::: "memory");

        __builtin_amdgcn_s_setprio(1);
#pragma unroll
        for (int s = 0; s < 2; s++) {
            bf16x8 pf = *(const bf16x8*)&Ps[wq][l16 * 72 + s * 32 + g * 8];
#pragma unroll
            for (int dt = 0; dt < 4; dt++) {
                bf16x8 vf = *(const bf16x8*)&Vt[(dt * 16 + l16) * 72 + s * 32 + g * 8];
                oa[dt] = __builtin_amdgcn_mfma_f32_16x16x32_bf16(pf, vf, oa[dt], 0, 0, 0);
            }
        }
        __builtin_amdgcn_s_setprio(0);
        __syncthreads();
    }

#pragma unroll
    for (int dt = 0; dt < 4; dt++)
#pragma unroll
        for (int r = 0; r < 4; r++) {
            int q = q0 + wq * 16 + 4 * g + r;
            float v = oa[dt][r] / l_r[r];
            o[(size_t)(bb * 576 + q) * 768 + h * 64 + dt * 16 + l16] = f2bf_bits(v);
        }
}

// ---------------- mean pool over 576 tokens (bf16 in) ----------------
__global__ __launch_bounds__(256) void pool_kernel(const __hip_bfloat16* __restrict__ tok,
                                                   float* __restrict__ pooled)
{
    int d = blockIdx.x * 256 + threadIdx.x;
    int b = blockIdx.y;
    float s = 0.0f;
    for (int n = 0; n < 576; n++) s += __bfloat162float(tok[(size_t)(b * 576 + n) * 768 + d]);
    pooled[b * 768 + d] = s * (1.0f / 576.0f);
}

// ---------------- classifier head ----------------
__global__ __launch_bounds__(256) void head_kernel(const float* __restrict__ lnp,
                                                   const float* __restrict__ w,
                                                   const float* __restrict__ bh,
                                                   float* __restrict__ out)
{
    int c = blockIdx.x * 256 + threadIdx.x;
    int b = blockIdx.y;
    if (c >= 1000) return;
    float s = bh[c];
    for (int d = 0; d < 768; d++) s += lnp[b * 768 + d] * w[(size_t)d * 1000 + c];
    out[b * 1000 + c] = s;
}

extern "C" void kernel_launch(void* const* d_in, const int* in_sizes, int n_in,
                              void* d_out, int out_size, void* d_ws, size_t ws_size,
                              hipStream_t stream)
{
    const float* x = (const float*)d_in[0];
    const float* patch_w = (const float*)d_in[1];
    const float* patch_b = (const float*)d_in[2];
    const float* ln1_g = (const float*)d_in[3];
    const float* ln1_b = (const float*)d_in[4];
    const float* w_qkv = (const float*)d_in[5];
    const float* bias_att = (const float*)d_in[6];
    const float* w_out = (const float*)d_in[7];
    const float* ln2_g = (const float*)d_in[8];
    const float* ln2_b = (const float*)d_in[9];
    const float* w1 = (const float*)d_in[10];
    const float* b1 = (const float*)d_in[11];
    const float* w2 = (const float*)d_in[12];
    const float* b2 = (const float*)d_in[13];
    const float* lnh_g = (const float*)d_in[14];
    const float* lnh_b = (const float*)d_in[15];
    const float* w_head = (const float*)d_in[16];
    const float* b_head = (const float*)d_in[17];
    float* out = (float*)d_out;

    char* ws = (char*)d_ws;
    __hip_bfloat16* tok = (__hip_bfloat16*)(ws + 0);             // 4608*768 bf16
    __hip_bfloat16* qkv_bf = (__hip_bfloat16*)(ws + 14155776);   // 4608*2304 bf16
    float* pooled = (float*)(ws + 56623104);
    float* pooledln = (float*)(ws + 56647680);
    __hip_bfloat16* patches = (__hip_bfloat16*)(ws + 56672256);  // 4608*1536 bf16
    __hip_bfloat16* lw = patches;                                // layer weights reuse after patch GEMM
    __hip_bfloat16* h_bf = (__hip_bfloat16*)(ws + 70828032);
    __hip_bfloat16* o_bf = (__hip_bfloat16*)(ws + 77905920);
    __hip_bfloat16* hid_bf = (__hip_bfloat16*)(ws + 84983808);
    __hip_bfloat16* wbuf = (__hip_bfloat16*)(ws + 113295360);    // patch weight 768*1536 bf16

    // patch embedding
    patchify_kernel<<<3456, 256, 0, stream>>>(x, (unsigned short*)patches);
    convT_patch_kernel<<<dim3(24, 48), 256, 0, stream>>>(patch_w, wbuf);
    gemm_bt_kernel<true, false><<<432, 256, 0, stream>>>(
        patches, wbuf, patch_b, nullptr, tok, 4608, 768, 1536, 6);

    for (int l = 0; l < 4; l++) {
        convT4_kernel<<<6912, 256, 0, stream>>>(
            w_qkv + (size_t)l * 768 * 2304, w_out + (size_t)l * 768 * 768,
            w1 + (size_t)l * 768 * 3072, w2 + (size_t)l * 3072 * 768, lw);
        // attn sub-block
        ln_kernel<__hip_bfloat16, __hip_bfloat16><<<4608, 256, 0, stream>>>(
            tok, ln1_g + l * 768, ln1_b + l * 768, h_bf);
        gemm_8ph_kernel<false, false><<<162, 512, 0, stream>>>(
            h_bf, lw, nullptr, qkv_bf, 4608, 2304, 768, 9);
        attn_kernel<<<864, 256, 0, stream>>>(
            qkv_bf, bias_att + (size_t)l * 12 * 576 * 576, (unsigned short*)o_bf);
        gemm_bt_kernel<false, true><<<432, 256, 0, stream>>>(
            o_bf, lw + 1769472, nullptr, tok, tok, 4608, 768, 768, 6);
        // mlp sub-block
        ln_kernel<__hip_bfloat16, __hip_bfloat16><<<4608, 256, 0, stream>>>(
            tok, ln2_g + l * 768, ln2_b + l * 768, h_bf);
        gemm_8ph_kernel<true, true><<<216, 512, 0, stream>>>(
            h_bf, lw + 2359296, b1 + l * 3072, hid_bf, 4608, 3072, 768, 12);
        gemm_bt_kernel<true, true><<<432, 256, 0, stream>>>(
            hid_bf, lw + 4718592, b2 + l * 768, tok, tok, 4608, 768, 3072, 6);
    }

    pool_kernel<<<dim3(3, 8), 256, 0, stream>>>(tok, pooled);
    ln_kernel<float, float><<<8, 256, 0, stream>>>(pooled, lnh_g, lnh_b, pooledln);
    head_kernel<<<dim3(4, 8), 256, 0, stream>>>(pooledln, w_head, b_head, out);
}